// Round 8
// baseline (191.057 us; speedup 1.0000x reference)
//
#include <hip/hip_runtime.h>
#include <math.h>

#define NN 50000
#define EE 400000
#define HD 256
#define NH 4
#define DH 64
#define NEG_SLOPE 0.2f
#define NTILES 3125   // 50000/16 exact

typedef __attribute__((ext_vector_type(8))) _Float16 f16x8;
typedef __attribute__((ext_vector_type(4))) float f32x4;

__device__ __forceinline__ float bf2f(unsigned short h) {
  return __uint_as_float(((unsigned)h) << 16);
}

// ============================ CSR build ============================
__global__ void k_zero_i32(int* __restrict__ p, int n) {
  int i = blockIdx.x * blockDim.x + threadIdx.x;
  if (i < n) p[i] = 0;
}

__global__ void k_count(const int* __restrict__ dst, int* __restrict__ counts,
                        int* __restrict__ rank) {
  int e = blockIdx.x * blockDim.x + threadIdx.x;
  if (e < EE) rank[e] = atomicAdd(&counts[dst[e]], 1);
}

__global__ void k_scan1(const int* __restrict__ counts, int* __restrict__ row_ptr,
                        int* __restrict__ bsums) {
  __shared__ int sm[256];
  int i = blockIdx.x * 256 + threadIdx.x;
  int v = (i < NN) ? counts[i] : 0;
  sm[threadIdx.x] = v;
  __syncthreads();
  for (int off = 1; off < 256; off <<= 1) {
    int t = (threadIdx.x >= off) ? sm[threadIdx.x - off] : 0;
    __syncthreads();
    sm[threadIdx.x] += t;
    __syncthreads();
  }
  if (i < NN) row_ptr[i + 1] = sm[threadIdx.x];
  if (threadIdx.x == 255) bsums[blockIdx.x] = sm[255];
}

__global__ void k_scan2(int* __restrict__ bsums, int nb) {
  __shared__ int sm[256];
  int v = (threadIdx.x < nb) ? bsums[threadIdx.x] : 0;
  sm[threadIdx.x] = v;
  __syncthreads();
  for (int off = 1; off < 256; off <<= 1) {
    int t = (threadIdx.x >= off) ? sm[threadIdx.x - off] : 0;
    __syncthreads();
    sm[threadIdx.x] += t;
    __syncthreads();
  }
  if (threadIdx.x < nb) bsums[threadIdx.x] = sm[threadIdx.x] - v;  // exclusive
}

__global__ void k_scan3(int* __restrict__ row_ptr, const int* __restrict__ bsums) {
  int i = blockIdx.x * 256 + threadIdx.x;
  if (i < NN) row_ptr[i + 1] += bsums[blockIdx.x];
  if (blockIdx.x == 0 && threadIdx.x == 0) row_ptr[0] = 0;
}

__global__ void k_scatter(const int* __restrict__ src, const int* __restrict__ dst,
                          const int* __restrict__ row_ptr, const int* __restrict__ rank,
                          int* __restrict__ csr_src) {
  int e = blockIdx.x * blockDim.x + threadIdx.x;
  if (e < EE) csr_src[row_ptr[dst[e]] + rank[e]] = src[e];
}

// ============================ W prep (fp16, pre-tiled) ============================
__global__ __launch_bounds__(256) void k_prep_w2(const float* __restrict__ W1,
                                                 const float* __restrict__ W2,
                                                 _Float16* __restrict__ W1t,
                                                 _Float16* __restrict__ W2t) {
  int b = blockIdx.x;
  const float* W = (b < 256) ? W1 : W2;
  _Float16* Wt = (b < 256) ? W1t : W2t;
  int t = (b & 255) * 256 + threadIdx.x;  // 65536
  int n = t & 255, k = t >> 8;
  float x = W[(size_t)k * 256 + n];
  size_t o = (size_t)(k >> 5) * 8192 + (size_t)((k >> 3) & 3) * 2048 + (size_t)n * 8 + (k & 7);
  Wt[o] = (_Float16)x;
}

// ============================ MFMA GEMM ============================
// f[M,256](bf16) = A[idx[m],256] @ W ; fp16-split A: (Ah+Al)@W(fp16).
// Whole W (128KB fp16, pre-tiled) in LDS, staged once, ONE barrier.
__device__ __forceinline__ void gload_lds16(const void* g, void* l) {
  __builtin_amdgcn_global_load_lds((const __attribute__((address_space(1))) void*)g,
                                   (__attribute__((address_space(3))) void*)l, 16, 0, 0);
}

__global__ __launch_bounds__(768, 3) void k_gemm_mfma(
    const float* __restrict__ A, const int* __restrict__ idx,
    const _Float16* __restrict__ Wt,
    const float* __restrict__ al, const float* __restrict__ ar,
    __bf16* __restrict__ C, float* __restrict__ el, float* __restrict__ er) {
  __shared__ f16x8 Bs[8192];  // 128KB

  int tid = threadIdx.x;
  int lane = tid & 63;
  int w = tid >> 6;           // 0..11
  int khalf = lane >> 4;
  int l15 = lane & 15;

  for (int i = tid; i < 8192; i += 768)
    gload_lds16(Wt + (size_t)i * 8, (void*)&Bs[i]);

  float alv[16], arv[16];
#pragma unroll
  for (int nf = 0; nf < 16; ++nf) {
    alv[nf] = al[nf * 16 + l15];
    arv[nf] = ar[nf * 16 + l15];
  }

  int nt = 1;
  int tiles[2];
  tiles[0] = blockIdx.x * 12 + w;
  int t2 = 3072 + blockIdx.x;
  if (w == 0 && t2 < NTILES) { tiles[1] = t2; nt = 2; }

  __syncthreads();  // the only barrier

  for (int it = 0; it < nt; ++it) {
    int t = tiles[it];
    int row = t * 16 + l15;
    int arow = idx ? idx[row] : row;
    const float* ap = A + (size_t)arow * HD + khalf * 8;

    f32x4 acc[16];
#pragma unroll
    for (int nf = 0; nf < 16; ++nf) acc[nf] = (f32x4){0.f, 0.f, 0.f, 0.f};

#pragma unroll 2
    for (int kb = 0; kb < 8; ++kb) {
      float xx[8];
      *(float4*)&xx[0] = *(const float4*)(ap + kb * 32);
      *(float4*)&xx[4] = *(const float4*)(ap + kb * 32 + 4);
      f16x8 ah, alo;
#pragma unroll
      for (int i = 0; i < 8; ++i) {
        _Float16 h = (_Float16)xx[i];
        ah[i] = h;
        alo[i] = (_Float16)(xx[i] - (float)h);
      }
#pragma unroll
      for (int nf = 0; nf < 16; ++nf) {
        f16x8 bv = Bs[kb * 1024 + khalf * 256 + nf * 16 + l15];
        acc[nf] = __builtin_amdgcn_mfma_f32_16x16x32_f16(ah, bv, acc[nf], 0, 0, 0);
        acc[nf] = __builtin_amdgcn_mfma_f32_16x16x32_f16(alo, bv, acc[nf], 0, 0, 0);
      }
    }

    int rowbase = t * 16 + khalf * 4;
#pragma unroll
    for (int r = 0; r < 4; ++r) {
      int row_ = rowbase + r;
      float seh[4], srh[4];
#pragma unroll
      for (int h = 0; h < 4; ++h) {
        float s1 = 0.f, s2 = 0.f;
#pragma unroll
        for (int j = 0; j < 4; ++j) {
          int nf = h * 4 + j;
          float v = acc[nf][r];
          s1 = fmaf(v, alv[nf], s1);
          s2 = fmaf(v, arv[nf], s2);
          C[(size_t)row_ * HD + nf * 16 + l15] = (__bf16)v;
        }
#pragma unroll
        for (int off = 1; off < 16; off <<= 1) {
          s1 += __shfl_xor(s1, off);
          s2 += __shfl_xor(s2, off);
        }
        seh[h] = s1;
        srh[h] = s2;
      }
      if (l15 == 0) {
        *(float4*)&el[row_ * NH] = make_float4(seh[0], seh[1], seh[2], seh[3]);
        *(float4*)&er[row_ * NH] = make_float4(srh[0], srh[1], srh[2], srh[3]);
      }
    }
  }
}

// ============================ aggregation ============================
// One wave per dst node. Softmax phases unchanged (regs for deg<=64).
// Gather: 32 lanes per edge, 16B/lane dwordx4 -> 2 edges per wave-instruction
// (halves VMEM instruction count at identical bytes).
__global__ __launch_bounds__(256) void k_aggregate(const __bf16* __restrict__ f,
                                                   const float* __restrict__ el,
                                                   const float* __restrict__ er,
                                                   const int* __restrict__ row_ptr,
                                                   const int* __restrict__ csr_src,
                                                   const float* __restrict__ bias,
                                                   float* __restrict__ out, int act) {
  int node = blockIdx.x * 4 + (threadIdx.x >> 6);
  if (node >= NN) return;
  int lane = threadIdx.x & 63;
  int start = row_ptr[node];
  int deg = row_ptr[node + 1] - start;

  float ern = er[node * NH + (lane & 3)];

  // ---- phase 1: per-head max (lane: edge c*16+(lane>>2), head lane&3) ----
  int sreg[4];
  float ereg[4];
  float mloc = -INFINITY;
#pragma unroll
  for (int c = 0; c < 4; ++c) {
    int j = c * 16 + (lane >> 2);
    int s = 0;
    float e = -INFINITY;
    if (c * 16 < deg && j < deg) {
      s = csr_src[start + j];
      e = el[s * NH + (lane & 3)] + ern;
      e = (e >= 0.f) ? e : NEG_SLOPE * e;
    }
    sreg[c] = s;
    ereg[c] = e;
    mloc = fmaxf(mloc, e);
  }
  for (int j0 = 64; j0 < deg; j0 += 16) {  // rare tail
    int j = j0 + (lane >> 2);
    if (j < deg) {
      int s = csr_src[start + j];
      float e = el[s * NH + (lane & 3)] + ern;
      e = (e >= 0.f) ? e : NEG_SLOPE * e;
      mloc = fmaxf(mloc, e);
    }
  }
  float mm = mloc;
#pragma unroll
  for (int off = 4; off < 64; off <<= 1) mm = fmaxf(mm, __shfl_xor(mm, off));

  // ---- phase 2: exp + sum ----
  float vreg[4];
  float vloc = 0.f;
#pragma unroll
  for (int c = 0; c < 4; ++c) {
    float v = (ereg[c] > -INFINITY) ? __expf(ereg[c] - mm) : 0.f;
    vreg[c] = v;
    vloc += v;
  }
  for (int j0 = 64; j0 < deg; j0 += 16) {  // rare tail
    int j = j0 + (lane >> 2);
    if (j < deg) {
      int s = csr_src[start + j];
      float e = el[s * NH + (lane & 3)] + ern;
      e = (e >= 0.f) ? e : NEG_SLOPE * e;
      vloc += __expf(e - mm);
    }
  }
  float ss = vloc;
#pragma unroll
  for (int off = 4; off < 64; off <<= 1) ss += __shfl_xor(ss, off);

  float inv_own = (ss > 0.f) ? (1.f / ss) : 0.f;
  float areg[4];
#pragma unroll
  for (int c = 0; c < 4; ++c) areg[c] = vreg[c] * inv_own;

  // ---- phase 3: gather-accumulate, 2 edges per wave-load ----
  int h = lane >> 5;        // half: which edge of the pair
  int l31 = lane & 31;      // 16B slot within the 512B row
  int headf = l31 >> 3;     // head of this lane's 8-feature range

  float acc[8];
#pragma unroll
  for (int i = 0; i < 8; ++i) acc[i] = 0.f;

  for (int c = 0; c < 4; ++c) {
    int base = c * 16;
    if (base >= deg) break;
    int cnt = deg - base;
    cnt = (cnt > 16) ? 16 : cnt;
    for (int g = 0; g < cnt; g += 8) {
      float4 raw[4];
      float aa[4];
#pragma unroll
      for (int p = 0; p < 4; ++p) {
        int j = g + 2 * p + h;
        int jc = (j < cnt) ? j : (cnt - 1);
        int srcl = (jc << 2) | headf;
        int s = __shfl(sreg[c], srcl);
        float a = __shfl(areg[c], srcl);
        aa[p] = (j < cnt) ? a : 0.f;
        raw[p] = ((const float4*)(f + (size_t)s * HD))[l31];
      }
#pragma unroll
      for (int p = 0; p < 4; ++p) {
        const unsigned* u = (const unsigned*)&raw[p];
#pragma unroll
        for (int k = 0; k < 4; ++k) {
          acc[2 * k] = fmaf(aa[p], __uint_as_float(u[k] << 16), acc[2 * k]);
          acc[2 * k + 1] = fmaf(aa[p], __uint_as_float(u[k] & 0xffff0000u), acc[2 * k + 1]);
        }
      }
    }
  }
  if (deg > 64) {  // rare tail: pair-process remaining edges
    float mH = __shfl(mm, headf);
    float sH = __shfl(ss, headf);
    float erH = __shfl(ern, headf);
    float invH = (sH > 0.f) ? (1.f / sH) : 0.f;
    for (int j0 = 64; j0 < deg; j0 += 2) {
      int j = j0 + h;
      int jc = (j < deg) ? j : (deg - 1);
      int s = csr_src[start + jc];
      float e = el[s * NH + headf] + erH;
      e = (e >= 0.f) ? e : NEG_SLOPE * e;
      float a = (j < deg) ? __expf(e - mH) * invH : 0.f;
      float4 raw = ((const float4*)(f + (size_t)s * HD))[l31];
      const unsigned* u = (const unsigned*)&raw;
#pragma unroll
      for (int k = 0; k < 4; ++k) {
        acc[2 * k] = fmaf(a, __uint_as_float(u[k] << 16), acc[2 * k]);
        acc[2 * k + 1] = fmaf(a, __uint_as_float(u[k] & 0xffff0000u), acc[2 * k + 1]);
      }
    }
  }

  // ---- epilogue: cross-half reduce, bias, ELU, one float4 store/lane ----
#pragma unroll
  for (int i = 0; i < 8; ++i) acc[i] += __shfl_xor(acc[i], 32);
  // lane (h=0) stores feats l31*8..+3 (acc[0..3]); (h=1) stores +4..+7 (acc[4..7])
  float4 r;
  r.x = h ? acc[4] : acc[0];
  r.y = h ? acc[5] : acc[1];
  r.z = h ? acc[6] : acc[2];
  r.w = h ? acc[7] : acc[3];
  float4 bv = ((const float4*)bias)[2 * l31 + h];
  r.x += bv.x; r.y += bv.y; r.z += bv.z; r.w += bv.w;
  if (act) {
    r.x = (r.x > 0.f) ? r.x : __expf(r.x) - 1.f;
    r.y = (r.y > 0.f) ? r.y : __expf(r.y) - 1.f;
    r.z = (r.z > 0.f) ? r.z : __expf(r.z) - 1.f;
    r.w = (r.w > 0.f) ? r.w : __expf(r.w) - 1.f;
  }
  ((float4*)(out + (size_t)node * HD))[2 * l31 + h] = r;
}

// ============================ launch ============================
extern "C" void kernel_launch(void* const* d_in, const int* in_sizes, int n_in,
                              void* d_out, int out_size, void* d_ws, size_t ws_size,
                              hipStream_t stream) {
  const int* nids = (const int*)d_in[0];
  const int* esrc = (const int*)d_in[1];
  const int* edst = (const int*)d_in[2];
  const float* emb = (const float*)d_in[3];
  const float* W1 = (const float*)d_in[4];
  const float* al1 = (const float*)d_in[5];
  const float* ar1 = (const float*)d_in[6];
  const float* b1 = (const float*)d_in[7];
  const float* W2 = (const float*)d_in[8];
  const float* al2 = (const float*)d_in[9];
  const float* ar2 = (const float*)d_in[10];
  const float* b2 = (const float*)d_in[11];
  float* out = (float*)d_out;

  char* w = (char*)d_ws;
  size_t off = 0;
  auto alloc = [&](size_t bytes) {
    void* p = w + off;
    off += (bytes + 255) & ~(size_t)255;
    return p;
  };
  __bf16* fbuf = (__bf16*)alloc((size_t)NN * HD * 2);
  float* el = (float*)alloc((size_t)NN * NH * 4);
  float* er = (float*)alloc((size_t)NN * NH * 4);
  int* row_ptr = (int*)alloc((size_t)(NN + 1) * 4);
  int* counts = (int*)alloc((size_t)NN * 4);
  int* rank = (int*)alloc((size_t)EE * 4);
  int* csr_src = (int*)alloc((size_t)EE * 4);
  int* bsums = (int*)alloc(1024);
  _Float16* W1t = (_Float16*)alloc((size_t)HD * HD * 2);
  _Float16* W2t = (_Float16*)alloc((size_t)HD * HD * 2);

  int nbN = (NN + 255) / 256;
  int nbE = (EE + 255) / 256;

  k_zero_i32<<<nbN, 256, 0, stream>>>(counts, NN);
  k_count<<<nbE, 256, 0, stream>>>(edst, counts, rank);
  k_scan1<<<nbN, 256, 0, stream>>>(counts, row_ptr, bsums);
  k_scan2<<<1, 256, 0, stream>>>(bsums, nbN);
  k_scan3<<<nbN, 256, 0, stream>>>(row_ptr, bsums);
  k_scatter<<<nbE, 256, 0, stream>>>(esrc, edst, row_ptr, rank, csr_src);
  k_prep_w2<<<512, 256, 0, stream>>>(W1, W2, W1t, W2t);

  int nbNode4 = (NN + 3) / 4;

  // ---- layer 1 ----
  k_gemm_mfma<<<256, 768, 0, stream>>>(emb, nids, W1t, al1, ar1, fbuf, el, er);
  k_aggregate<<<nbNode4, 256, 0, stream>>>(fbuf, el, er, row_ptr, csr_src, b1, out, 1);

  // ---- layer 2 ----
  k_gemm_mfma<<<256, 768, 0, stream>>>(out, nullptr, W2t, al2, ar2, fbuf, el, er);
  k_aggregate<<<nbNode4, 256, 0, stream>>>(fbuf, el, er, row_ptr, csr_src, b2, out, 0);
}